// Round 4
// baseline (93.385 us; speedup 1.0000x reference)
//
#include <hip/hip_runtime.h>
#include <hip/hip_bf16.h>
#include <stdint.h>

// KAN layer: out[n,o] = sum_j w[o,j] * spline(x[n,j]; coeffs[o,j,:]) + bias[o]
// N=1024, D_IN=128, D_OUT=128, K=8 knots, Catmull-Rom on uniform grid [-1,1].
//
// Dense-basis reformulation: per (n,j) build an 8-wide basis vector (4 nonzero
// Catmull-Rom weights accumulated into knot slots; accumulation handles the
// boundary i0/i3 clipping aliasing). Each edge is then a dot8 against
// coeffs[o,j,0:8], scaled by w[o,j].
//
// Dtype evidence (R0-R2): R1 bf16-read -> NaN proves inputs are fp32.
// R2 error 5.22 matches "wrote bf16 into an fp32 output buffer" pattern
// (checker word i ~ ref[2i+1] vs ref[i], predicted max ~5.1). Policy: dataset
// converts all-or-nothing, so output dtype follows the input sniff.
// Sniff: low 16 bits of first 64 words of x are valid bf16 in [-1,1] iff the
// buffer is bf16 (fp32 mantissa bits pass with p~0.5/lane -> ballot filters).
// R3 was an infra failure (Trio nursery) -- resubmitting unchanged.

#define DIN 128
#define DOUT 128
#define KK 8
#define TN 4

typedef unsigned int u32;
typedef unsigned short u16;

union U4 { uint4 v; u16 s[8]; };

__device__ __forceinline__ float bf2f(u16 a) {
    union { u32 u; float f; } c; c.u = ((u32)a) << 16; return c.f;
}

template<bool B16>
__device__ __forceinline__ float ld1(const void* p, int i) {
    return B16 ? bf2f(((const u16*)p)[i]) : ((const float*)p)[i];
}

// Load 8 consecutive values starting at element i (i % 8 == 0) as fp32.
template<bool B16>
__device__ __forceinline__ void ld8(const void* p, int i, float* f) {
    if (B16) {
        U4 c; c.v = *(const uint4*)((const u16*)p + i);
        #pragma unroll
        for (int k = 0; k < 8; ++k) f[k] = bf2f(c.s[k]);
    } else {
        float4 a = *(const float4*)((const float*)p + i);
        float4 b = *(const float4*)((const float*)p + i + 4);
        f[0] = a.x; f[1] = a.y; f[2] = a.z; f[3] = a.w;
        f[4] = b.x; f[5] = b.y; f[6] = b.z; f[7] = b.w;
    }
}

template<bool B16>
__device__ __forceinline__ void st1(void* p, int i, float v) {
    if (B16) ((__hip_bfloat16*)p)[i] = __float2bfloat16(v);
    else     ((float*)p)[i] = v;
}

template<bool B16>
__device__ __forceinline__ void run_kan(
    const void* __restrict__ x, const void* __restrict__ coeffs,
    const void* __restrict__ weights, const void* __restrict__ bias,
    void* __restrict__ out, float* sb, int n0, int tid)
{
    // ---- Phase 1: dense basis vectors for TN rows x DIN inputs ----
    #pragma unroll
    for (int pp = 0; pp < 2; ++pp) {
        const int p = tid + pp * 256;          // p in [0, 512)
        const int row = p >> 7;                // DIN = 128
        const int j = p & 127;
        float xv = ld1<B16>(x, (n0 + row) * DIN + j);
        xv = fminf(fmaxf(xv, -1.0f), 1.0f);
        const float t = (xv + 1.0f) * 3.5f;    // /h, h = 2/(K-1) = 2/7
        int idx = (int)t; idx = idx > 6 ? 6 : idx;   // t >= 0 so trunc==floor
        const float u = t - (float)idx;
        const float u2 = u * u, u3 = u2 * u;
        const float b0 = 0.5f * (-u3 + 2.0f * u2 - u);
        const float b1 = 0.5f * (3.0f * u3 - 5.0f * u2 + 2.0f);
        const float b2 = 0.5f * (-3.0f * u3 + 4.0f * u2 + u);
        const float b3 = 0.5f * (u3 - u2);
        float* r = sb + p * KK;
        #pragma unroll
        for (int k = 0; k < KK; ++k) r[k] = 0.0f;
        int i0 = idx - 1; i0 = i0 < 0 ? 0 : i0;      // clip -> accumulate
        int i3 = idx + 2; i3 = i3 > 7 ? 7 : i3;
        r[i0] += b0; r[idx] += b1; r[idx + 1] += b2; r[i3] += b3;
    }
    __syncthreads();

    // ---- Phase 2: accumulate 2 rows per thread ----
    const int o = tid & 127;
    const int ng = tid >> 7;                   // 0 or 1; rows ng and ng+2
    const int cbase = o * (DIN * KK);
    const int wbase = o * DIN;
    const float4* sA = (const float4*)(sb + (ng + 0) * DIN * KK);
    const float4* sB = (const float4*)(sb + (ng + 2) * DIN * KK);
    float accA = 0.0f, accB = 0.0f;

    for (int j0 = 0; j0 < DIN; j0 += 8) {
        float w8[8];
        ld8<B16>(weights, wbase + j0, w8);
        #pragma unroll
        for (int jj = 0; jj < 8; ++jj) {
            const int j = j0 + jj;
            float cf[8];
            ld8<B16>(coeffs, cbase + j * KK, cf);
            const float4 a0 = sA[j * 2], a1 = sA[j * 2 + 1];  // broadcast
            const float4 e0 = sB[j * 2], e1 = sB[j * 2 + 1];  // broadcast
            float dA = a0.x * cf[0];
            dA = fmaf(a0.y, cf[1], dA); dA = fmaf(a0.z, cf[2], dA);
            dA = fmaf(a0.w, cf[3], dA); dA = fmaf(a1.x, cf[4], dA);
            dA = fmaf(a1.y, cf[5], dA); dA = fmaf(a1.z, cf[6], dA);
            dA = fmaf(a1.w, cf[7], dA);
            float dB = e0.x * cf[0];
            dB = fmaf(e0.y, cf[1], dB); dB = fmaf(e0.z, cf[2], dB);
            dB = fmaf(e0.w, cf[3], dB); dB = fmaf(e1.x, cf[4], dB);
            dB = fmaf(e1.y, cf[5], dB); dB = fmaf(e1.z, cf[6], dB);
            dB = fmaf(e1.w, cf[7], dB);
            accA = fmaf(w8[jj], dA, accA);
            accB = fmaf(w8[jj], dB, accB);
        }
    }

    const float bv = ld1<B16>(bias, o);
    st1<B16>(out, (n0 + ng + 0) * DOUT + o, accA + bv);
    st1<B16>(out, (n0 + ng + 2) * DOUT + o, accB + bv);
}

__global__ __launch_bounds__(256) void kan_kernel(
    const void* __restrict__ x, const void* __restrict__ coeffs,
    const void* __restrict__ weights, const void* __restrict__ bias,
    void* __restrict__ out)
{
    __shared__ float sb[TN * DIN * KK];   // 16 KB: [row][j][k]
    const int tid = threadIdx.x;
    const int n0 = blockIdx.x * TN;

    // ---- dtype sniff (block-uniform, deterministic, graph-safe) ----
    const u32 w = ((const u32*)x)[tid & 63];
    const float probe = bf2f((u16)(w & 0xFFFFu));
    const bool ok = (probe >= -1.0f) && (probe <= 1.0f);   // NaN fails
    const unsigned long long m = __ballot(ok);
    const bool is_bf16 = (__popcll(m) >= 48);

    if (is_bf16)
        run_kan<true>(x, coeffs, weights, bias, out, sb, n0, tid);
    else
        run_kan<false>(x, coeffs, weights, bias, out, sb, n0, tid);
}

extern "C" void kernel_launch(void* const* d_in, const int* in_sizes, int n_in,
                              void* d_out, int out_size, void* d_ws, size_t ws_size,
                              hipStream_t stream) {
    const void* x       = d_in[0];
    const void* coeffs  = d_in[1];
    const void* weights = d_in[2];
    const void* bias    = d_in[3];
    const int N = in_sizes[0] / DIN;            // 1024
    kan_kernel<<<N / TN, 256, 0, stream>>>(x, coeffs, weights, bias, d_out);
}

// Round 5
// 65.320 us; speedup vs baseline: 1.4297x; 1.4297x over previous
//
#include <hip/hip_runtime.h>
#include <hip/hip_bf16.h>
#include <stdint.h>

// KAN layer: out[n,o] = sum_j w[o,j] * spline(x[n,j]; coeffs[o,j,:]) + bias[o]
// N=1024, D_IN=128, D_OUT=128, K=8 knots, Catmull-Rom, uniform grid [-1,1].
//
// R4 post-mortem: VALU kernel passed (absmax 3.9e-3) at 40us dispatch but
// VALUBusy=11%, Occupancy=10% -> latency-bound on per-lane coeff streams
// (4KB lane stride = 64 cache lines per dwordx4, ~32K serialized L1 line
// requests per block).
//
// R5: GEMM reformulation. out = B @ W'^T with
//   B[n, j*8+k]  = dense Catmull-Rom basis (4 nonzeros accumulated into 8
//                  knot slots; accumulation handles boundary clipping),
//   W'[o, j*8+k] = w[o,j] * c[o,j,k]   (built per-block from coalesced reads)
// M=1024, N=128(out cols), K=1024. mfma_f32_16x16x32_bf16, fp32 accumulate.
// Block: 16 m-rows x 16 o-cols, K chunked by 256, 4 waves split K, LDS
// reduction. Grid 64x8=512 blocks -> 2 blocks/CU. All global reads coalesced.
// Inputs/outputs fp32 (proven R1/R2/R4). bf16 error est ~0.02 < 0.0703 thr.

#define DIN 128
#define DOUT 128
#define KK 8
#define KTOT 1024      // DIN*KK
#define MT 16          // rows (n) per block
#define OT 16          // cols (o) per block
#define KC 256         // k per chunk
#define JC 32          // j per chunk
#define SW 264         // padded LDS row length in u16 (KC + 8); 528B = 33*16

typedef unsigned int u32;
typedef unsigned short u16;
typedef __attribute__((ext_vector_type(8))) short bf16x8;
typedef __attribute__((ext_vector_type(4))) float f32x4;

union H8 { u16 s[8]; uint4 v; };

__device__ __forceinline__ u16 f2b(float f) {
    __hip_bfloat16 h = __float2bfloat16(f);   // RNE
    union { __hip_bfloat16 h; u16 u; } c; c.h = h; return c.u;
}

__global__ __launch_bounds__(256) void kan_mfma(
    const float* __restrict__ x, const float* __restrict__ coeffs,
    const float* __restrict__ weights, const float* __restrict__ bias,
    float* __restrict__ out)
{
    __shared__ __align__(16) u16 sA[MT * SW];   // 8448 B basis tile (bf16)
    __shared__ __align__(16) u16 sB[OT * SW];   // 8448 B W' tile (bf16)
    __shared__ float sC[4 * MT * OT];           // 4096 B wave partials

    const int tid  = threadIdx.x;
    const int wave = tid >> 6;
    const int lane = tid & 63;
    const int n0 = blockIdx.x * MT;             // 64 m-tiles
    const int o0 = blockIdx.y * OT;             // 8 o-tiles

    const int m = lane & 15;                    // MFMA row/col within frag
    const int q = lane >> 4;                    // k-quad

    f32x4 acc = {0.0f, 0.0f, 0.0f, 0.0f};

    for (int ch = 0; ch < 4; ++ch) {
        // ---- stage W' chunk: sB[o_local][kc] = w[o][kg>>3] * c[o][kg] ----
        // per iter, each wave covers one full o-row (w broadcast-uniform).
        #pragma unroll
        for (int i = 0; i < 4; ++i) {
            const int ol = i * 4 + wave;        // 0..15
            const int kc = lane * 4;            // 0..252
            const int kg = ch * KC + kc;        // global k
            const float4 c4 = *(const float4*)(coeffs + (o0 + ol) * KTOT + kg);
            const float wv = weights[(o0 + ol) * DIN + (kg >> 3)];
            ushort4 b;
            b.x = f2b(c4.x * wv); b.y = f2b(c4.y * wv);
            b.z = f2b(c4.z * wv); b.w = f2b(c4.w * wv);
            *(ushort4*)(sB + ol * SW + kc) = b;
        }

        // ---- stage basis chunk: sA[row][jl*8 + k] ----
        #pragma unroll
        for (int it = 0; it < 2; ++it) {
            const int task = tid + it * 256;    // 512 tasks = 16 rows x 32 j
            const int row = task >> 5;
            const int jl = task & 31;
            const int j = ch * JC + jl;
            float xv = x[(n0 + row) * DIN + j];
            xv = fminf(fmaxf(xv, -1.0f), 1.0f);
            const float t = (xv + 1.0f) * 3.5f; // h = 2/7
            int idx = (int)t; idx = idx > 6 ? 6 : idx;
            const float u = t - (float)idx;
            const float u2 = u * u, u3 = u2 * u;
            const float b0 = 0.5f * (-u3 + 2.0f * u2 - u);
            const float b1 = 0.5f * (3.0f * u3 - 5.0f * u2 + 2.0f);
            const float b2 = 0.5f * (-3.0f * u3 + 4.0f * u2 + u);
            const float b3 = 0.5f * (u3 - u2);
            float r[8];
            #pragma unroll
            for (int k = 0; k < 8; ++k) r[k] = 0.0f;
            int i0 = idx - 1; i0 = i0 < 0 ? 0 : i0;
            int i3 = idx + 2; i3 = i3 > 7 ? 7 : i3;
            r[i0] += b0; r[idx] += b1; r[idx + 1] += b2; r[i3] += b3;
            H8 h;
            #pragma unroll
            for (int k = 0; k < 8; ++k) h.s[k] = f2b(r[k]);
            *(uint4*)(sA + row * SW + jl * 8) = h.v;
        }
        __syncthreads();

        // ---- MFMA: this wave's k-quarter of the chunk (64 k = 2 steps) ----
        const int kq = wave * 64;
        #pragma unroll
        for (int s = 0; s < 2; ++s) {
            const int kk = kq + s * 32 + q * 8;
            bf16x8 af = *(const bf16x8*)(sA + m * SW + kk);  // A[m][k..k+7]
            bf16x8 bf = *(const bf16x8*)(sB + m * SW + kk);  // W'[o][k..k+7]
            acc = __builtin_amdgcn_mfma_f32_16x16x32_bf16(af, bf, acc, 0, 0, 0);
        }
        __syncthreads();   // before next chunk overwrites sA/sB
    }

    // ---- epilogue: reduce 4 wave partials, add bias, store ----
    // C/D layout: col = lane&15, row = (lane>>4)*4 + reg  [m89-verified]
    #pragma unroll
    for (int r = 0; r < 4; ++r) {
        const int row = q * 4 + r;
        sC[wave * (MT * OT) + row * OT + m] = acc[r];
    }
    __syncthreads();
    const int orow = tid >> 4;                  // n within tile
    const int ocol = tid & 15;                  // o within tile
    float v = sC[tid] + sC[256 + tid] + sC[512 + tid] + sC[768 + tid];
    v += bias[o0 + ocol];
    out[(n0 + orow) * DOUT + o0 + ocol] = v;
}

extern "C" void kernel_launch(void* const* d_in, const int* in_sizes, int n_in,
                              void* d_out, int out_size, void* d_ws, size_t ws_size,
                              hipStream_t stream) {
    const float* x       = (const float*)d_in[0];
    const float* coeffs  = (const float*)d_in[1];
    const float* weights = (const float*)d_in[2];
    const float* bias    = (const float*)d_in[3];
    float* out = (float*)d_out;
    const int N = in_sizes[0] / DIN;            // 1024
    dim3 grid(N / MT, DOUT / OT);               // 64 x 8 = 512 blocks
    kan_mfma<<<grid, 256, 0, stream>>>(x, coeffs, weights, bias, out);
}

// Round 6
// 65.116 us; speedup vs baseline: 1.4341x; 1.0031x over previous
//
#include <hip/hip_runtime.h>
#include <hip/hip_bf16.h>
#include <stdint.h>

// KAN layer: out[n,o] = sum_j w[o,j] * spline(x[n,j]; coeffs[o,j,:]) + bias[o]
// N=1024, D_IN=128, D_OUT=128, K=8, Catmull-Rom, uniform grid [-1,1].
// fp32 in/out (proven R1/R2/R4).
//
// R5 post-mortem: MFMA rewrite -> kernel ~13us (dur 93->65; fills+overhead
// are a fixed ~52us). Residual cost: 8 barrier-drained staging rounds per
// block + W' restaged every chunk + cross-wave reduce.
//
// R6: basis staged ONCE per block (full K=1024) in LDS; W' fragments built
// directly in registers from coalesced-ish global loads (lane (o,q) needs
// exactly w[o,j]*c[o,j,0:8] contiguous = 32B). 3 barriers total.
// Block 256thr = 4 waves = 2 o-tiles x 2-way K-split; grid 64x4=256 blocks
// -> 1024 waves = 1 per SIMD chip-wide.
//
// MFMA 16x16x32 bf16 layouts (verified in R5, m89): A-frag lane holds
// A[m=lane&15][k=(lane>>4)*8+j]; B-frag lane holds B[o=lane&15][same k];
// C/D: col=lane&15, row=(lane>>4)*4+reg.

#define DIN 128
#define DOUT 128
#define KTOT 1024
#define MT 16
#define PADW 1032   // halfwords per basis row (1024 + 8): frag reads uniform

typedef unsigned int u32;
typedef unsigned short u16;
typedef __attribute__((ext_vector_type(8))) short bf16x8;
typedef __attribute__((ext_vector_type(4))) float f32x4;

__device__ __forceinline__ u16 f2b(float f) {
    union { __hip_bfloat16 h; u16 u; } c;
    c.h = __float2bfloat16(f);   // RNE
    return c.u;
}

__global__ __launch_bounds__(256) void kan_mfma(
    const float* __restrict__ x, const float* __restrict__ coeffs,
    const float* __restrict__ weights, const float* __restrict__ bias,
    float* __restrict__ out)
{
    __shared__ __align__(16) u16 sA[MT * PADW];   // 33 KB basis (bf16)
    __shared__ float sC[4 * 256];                 // 4 KB wave partials

    const int tid  = threadIdx.x;
    const int wave = tid >> 6;
    const int lane = tid & 63;
    const int n0 = blockIdx.x * MT;               // 64 m-tiles
    const int og = blockIdx.y * 32;               // 4 o-groups of 32

    // ---- Phase 0: zero the used basis region (2048 uint4 = 8/thread) ----
    #pragma unroll
    for (int it = 0; it < 8; ++it) {
        const int z = tid + it * 256;             // [0,2048)
        const int row = z >> 7, c16 = z & 127;
        *(uint4*)(sA + row * PADW + c16 * 8) = uint4{0u, 0u, 0u, 0u};
    }
    __syncthreads();

    // ---- Phase 1: scatter dense basis (2048 tasks = 8/thread) ----
    #pragma unroll
    for (int it = 0; it < 8; ++it) {
        const int task = tid + it * 256;
        const int row = task >> 7;                // 0..15
        const int j = task & 127;
        float xv = x[(n0 + row) * DIN + j];       // coalesced
        xv = fminf(fmaxf(xv, -1.0f), 1.0f);
        const float t = (xv + 1.0f) * 3.5f;       // h = 2/7
        int idx = (int)t; idx = idx > 6 ? 6 : idx;
        const float u = t - (float)idx;
        const float u2 = u * u, u3 = u2 * u;
        const float b0 = 0.5f * (-u3 + 2.0f * u2 - u);
        const float b1 = 0.5f * (3.0f * u3 - 5.0f * u2 + 2.0f);
        const float b2 = 0.5f * (-3.0f * u3 + 4.0f * u2 + u);
        const float b3 = 0.5f * (u3 - u2);
        u16* r = sA + row * PADW + j * 8;
        const int i0 = idx > 0 ? idx - 1 : 0;
        const int i3 = idx < 6 ? idx + 2 : 7;
        r[idx]     = f2b(b1);                     // same-thread order holds
        r[idx + 1] = f2b(b2);
        r[i0]      = f2b(idx == 0 ? b0 + b1 : b0);
        r[i3]      = f2b(idx == 6 ? b2 + b3 : b3);
    }
    __syncthreads();

    // ---- Phase 2: MFMA. wave -> (o-tile, k-half) ----
    const int ot = wave & 1;                      // o-tile within group
    const int kh = wave >> 1;                     // k-half
    const int mo = lane & 15;                     // A-row / B-o-row / D-col
    const int q  = lane >> 4;                     // k-quad

    const int orow = og + ot * 16 + mo;
    const float* cp = coeffs + orow * KTOT + kh * 512 + q * 8;
    const float* wp = weights + orow * DIN + kh * 64 + q;
    const u16*   ap = sA + mo * PADW + kh * 512 + q * 8;

    f32x4 acc = {0.0f, 0.0f, 0.0f, 0.0f};
    #pragma unroll 4
    for (int s = 0; s < 16; ++s) {
        bf16x8 af = *(const bf16x8*)(ap + s * 32);
        const float4 c0 = *(const float4*)(cp + s * 32);
        const float4 c1 = *(const float4*)(cp + s * 32 + 4);
        const float wv = wp[s * 4];
        bf16x8 bfr;
        bfr[0] = (short)f2b(c0.x * wv); bfr[1] = (short)f2b(c0.y * wv);
        bfr[2] = (short)f2b(c0.z * wv); bfr[3] = (short)f2b(c0.w * wv);
        bfr[4] = (short)f2b(c1.x * wv); bfr[5] = (short)f2b(c1.y * wv);
        bfr[6] = (short)f2b(c1.z * wv); bfr[7] = (short)f2b(c1.w * wv);
        acc = __builtin_amdgcn_mfma_f32_16x16x32_bf16(af, bfr, acc, 0, 0, 0);
    }

    // ---- Phase 3: pairwise K-half reduce + bias + store ----
    #pragma unroll
    for (int r = 0; r < 4; ++r)
        sC[wave * 256 + (q * 4 + r) * 16 + mo] = acc[r];
    __syncthreads();

    #pragma unroll
    for (int t2 = 0; t2 < 2; ++t2) {
        const int e = tid + t2 * 256;             // [0,512)
        const int tile = e >> 8;                  // o-tile
        const int idx = e & 255;
        const int row = idx >> 4, col = idx & 15;
        float v = sC[tile * 256 + idx] + sC[(tile + 2) * 256 + idx];
        const int oc = og + tile * 16 + col;
        out[(n0 + row) * DOUT + oc] = v + bias[oc];
    }
}

extern "C" void kernel_launch(void* const* d_in, const int* in_sizes, int n_in,
                              void* d_out, int out_size, void* d_ws, size_t ws_size,
                              hipStream_t stream) {
    const float* x       = (const float*)d_in[0];
    const float* coeffs  = (const float*)d_in[1];
    const float* weights = (const float*)d_in[2];
    const float* bias    = (const float*)d_in[3];
    float* out = (float*)d_out;
    const int N = in_sizes[0] / DIN;              // 1024
    dim3 grid(N / MT, DOUT / 32);                 // 64 x 4 = 256 blocks
    kan_mfma<<<grid, 256, 0, stream>>>(x, coeffs, weights, bias, out);
}